// Round 6
// baseline (528.854 us; speedup 1.0000x reference)
//
#include <hip/hip_runtime.h>
#include <math.h>

#define NSLOPE 0.2f

typedef __attribute__((ext_vector_type(8))) short  bf16x8;
typedef __attribute__((ext_vector_type(4))) float  floatx4;

__device__ __forceinline__ unsigned short f2bf(float f) {
    unsigned u = __builtin_bit_cast(unsigned, f);
    u += 0x7fff + ((u >> 16) & 1);          // RNE
    return (unsigned short)(u >> 16);
}
__device__ __forceinline__ float bf2f(unsigned short h) {
    unsigned u = (unsigned)h << 16;
    return __builtin_bit_cast(float, u);
}

__device__ __forceinline__ void split8(const float* v, bf16x8& hi, bf16x8& lo) {
#pragma unroll
    for (int j = 0; j < 8; j++) {
        unsigned short h = f2bf(v[j]);
        hi[j] = (short)h;
        lo[j] = (short)f2bf(v[j] - bf2f(h));
    }
}

__device__ __forceinline__ void unpack8(uint4 a, uint4 b, bf16x8& hi, bf16x8& lo) {
    unsigned w[8] = {a.x, a.y, a.z, a.w, b.x, b.y, b.z, b.w};
#pragma unroll
    for (int j = 0; j < 8; j++) {
        hi[j] = (short)(w[j] & 0xFFFFu);
        lo[j] = (short)(w[j] >> 16);
    }
}

// ============================================================
// h-projection + alpha fold (unchanged from R4/R5 — 3-term)
// ============================================================
__global__ __launch_bounds__(256, 2)
void hproj_kernel(const float* __restrict__ x,
                  const unsigned short* __restrict__ Bhi,
                  const unsigned short* __restrict__ Blo,
                  const float* __restrict__ asrc, const float* __restrict__ adst,
                  float* __restrict__ h, float* __restrict__ alS,
                  float* __restrict__ alD, int M)
{
    const int lane = threadIdx.x & 63;
    const int wv   = threadIdx.x >> 6;
    const int l15  = lane & 15;
    const int quad = lane >> 4;
    const int m0   = blockIdx.x * 128 + wv * 32;

    floatx4 acc[2][4];
#pragma unroll
    for (int mt = 0; mt < 2; mt++)
#pragma unroll
        for (int nt = 0; nt < 4; nt++) acc[mt][nt] = (floatx4){0.f, 0.f, 0.f, 0.f};

    int r0 = m0 + l15;      if (r0 >= M) r0 = M - 1;
    int r1 = m0 + 16 + l15; if (r1 >= M) r1 = M - 1;
    const float* a0 = x + (size_t)r0 * 130 + 2 + quad * 8;
    const float* a1 = x + (size_t)r1 * 130 + 2 + quad * 8;

#pragma unroll
    for (int kt = 0; kt < 4; kt++) {
        const int kb = kt * 32;
        float av[2][8];
#pragma unroll
        for (int j = 0; j < 4; j++) {
            float2 q0 = *(const float2*)(a0 + kb + 2 * j);
            float2 q1 = *(const float2*)(a1 + kb + 2 * j);
            av[0][2 * j] = q0.x; av[0][2 * j + 1] = q0.y;
            av[1][2 * j] = q1.x; av[1][2 * j + 1] = q1.y;
        }
        bf16x8 ah[2], al[2];
        split8(av[0], ah[0], al[0]);
        split8(av[1], ah[1], al[1]);
#pragma unroll
        for (int nt = 0; nt < 4; nt++) {
            const size_t boff = (size_t)(nt * 16 + l15) * 128 + kb + quad * 8;
            bf16x8 bh = *(const bf16x8*)(Bhi + boff);
            bf16x8 bl = *(const bf16x8*)(Blo + boff);
#pragma unroll
            for (int mt = 0; mt < 2; mt++) {
                acc[mt][nt] = __builtin_amdgcn_mfma_f32_16x16x32_bf16(ah[mt], bh, acc[mt][nt], 0, 0, 0);
                acc[mt][nt] = __builtin_amdgcn_mfma_f32_16x16x32_bf16(ah[mt], bl, acc[mt][nt], 0, 0, 0);
                acc[mt][nt] = __builtin_amdgcn_mfma_f32_16x16x32_bf16(al[mt], bh, acc[mt][nt], 0, 0, 0);
            }
        }
    }

    float as4[4], ad4[4];
#pragma unroll
    for (int nt = 0; nt < 4; nt++) {
        as4[nt] = asrc[nt * 16 + l15];
        ad4[nt] = adst[nt * 16 + l15];
    }

    float ps[2][4], pd[2][4];
#pragma unroll
    for (int mt = 0; mt < 2; mt++) {
#pragma unroll
        for (int r = 0; r < 4; r++) {
            int row = m0 + mt * 16 + quad * 4 + r;
            float s = 0.f, d = 0.f;
#pragma unroll
            for (int nt = 0; nt < 4; nt++) {
                float v = acc[mt][nt][r];
                s += v * as4[nt];
                d += v * ad4[nt];
                if (row < M) h[(size_t)row * 64 + nt * 16 + l15] = v;
            }
            ps[mt][r] = s; pd[mt][r] = d;
        }
    }
#pragma unroll
    for (int mt = 0; mt < 2; mt++)
#pragma unroll
        for (int r = 0; r < 4; r++) {
#pragma unroll
            for (int msk = 1; msk < 16; msk <<= 1) {
                ps[mt][r] += __shfl_xor(ps[mt][r], msk);
                pd[mt][r] += __shfl_xor(pd[mt][r], msk);
            }
        }
    if (l15 == 0) {
#pragma unroll
        for (int mt = 0; mt < 2; mt++)
#pragma unroll
            for (int r = 0; r < 4; r++) {
                int row = m0 + mt * 16 + quad * 4 + r;
                if (row < M) { alS[row] = ps[mt][r]; alD[row] = pd[mt][r]; }
            }
    }
}

// ============================================================
// Fused MLP v3: WAVE-PRIVATE, zero barriers, no spills.
// Each wave owns 16 rows and a 12544 B LDS slice.
//   fc1: 24 nt x 2 kt x 2-term (A hi+lo x B hi)     -> h1 bf16-hi in LDS
//   fc2: 12 kt x 8 nt x 1-term (h1-hi x B hi)       -> h2 hi|lo u32 (overlaid)
//   fc3: 4 kt x 4 nt x 3-term                        -> out
// Same-wave DS ops are processed in order -> overlay is safe
// (all h1 reads issue before any h2 write).
// ============================================================
__global__ __launch_bounds__(256, 4)
void fused_mlp(const float* __restrict__ x3,
               const float* __restrict__ x,
               const unsigned short* __restrict__ f1Hi,
               const unsigned short* __restrict__ f2Hi,
               const unsigned short* __restrict__ f3Hi,
               const unsigned short* __restrict__ f3Lo,
               const float* __restrict__ cb, const float* __restrict__ u1,
               const float* __restrict__ u2, const float* __restrict__ fc2b,
               const float* __restrict__ fc3b,
               float* __restrict__ out, int M)
{
    __shared__ unsigned short smem[4 * 6272];             // 50176 B total
    const int lane = threadIdx.x & 63;
    const int wv   = threadIdx.x >> 6;
    const int l15  = lane & 15;
    const int quad = lane >> 4;
    const int m0   = blockIdx.x * 64 + wv * 16;

    unsigned short* h1s = smem + wv * 6272;               // [16][392] bf16-hi
    unsigned int*   h2s = (unsigned int*)h1s;             // [16][132] u32 overlay

    // ---- fc1 A-frags from x3 (K=64), hi+lo split ----
    bf16x8 ah[2], al[2];
    {
        int r0 = m0 + l15; if (r0 >= M) r0 = M - 1;
        const float* a0 = x3 + (size_t)r0 * 64 + quad * 8;
#pragma unroll
        for (int kt = 0; kt < 2; kt++) {
            float av[8];
            float4 qa = *(const float4*)(a0 + kt * 32);
            float4 qb = *(const float4*)(a0 + kt * 32 + 4);
            av[0]=qa.x; av[1]=qa.y; av[2]=qa.z; av[3]=qa.w;
            av[4]=qb.x; av[5]=qb.y; av[6]=qb.z; av[7]=qb.w;
            split8(av, ah[kt], al[kt]);
        }
    }

    // rank-1 row scalars for this lane's epilogue rows (quad*4+r)
    float xv0[4], xv1[4];
#pragma unroll
    for (int r = 0; r < 4; r++) {
        int row = m0 + quad * 4 + r;
        float2 xv = {0.f, 0.f};
        if (row < M) xv = *(const float2*)(x + (size_t)row * 130);
        xv0[r] = xv.x; xv1[r] = xv.y;
    }

    // ---- fc1: 24 col-tiles, immediate epilogue -> h1s ----
#pragma unroll 4
    for (int nt = 0; nt < 24; nt++) {
        floatx4 acc = (floatx4){0.f, 0.f, 0.f, 0.f};
        const int col = nt * 16 + l15;
        const size_t cb0 = (size_t)col * 64 + quad * 8;
#pragma unroll
        for (int kt = 0; kt < 2; kt++) {
            bf16x8 bh = *(const bf16x8*)(f1Hi + cb0 + kt * 32);
            acc = __builtin_amdgcn_mfma_f32_16x16x32_bf16(ah[kt], bh, acc, 0, 0, 0);
            acc = __builtin_amdgcn_mfma_f32_16x16x32_bf16(al[kt], bh, acc, 0, 0, 0);
        }
        float c0 = cb[col], uu1 = u1[col], uu2 = u2[col];
#pragma unroll
        for (int r = 0; r < 4; r++) {
            float v = acc[r] + c0 + xv0[r] * uu1 + xv1[r] * uu2;
            v = v > 0.f ? v : 0.f;
            h1s[(quad * 4 + r) * 392 + col] = f2bf(v);
        }
    }

    // ---- fc2: K=384, 8 col-tiles, 1-term ----
    floatx4 acc2[8];
#pragma unroll
    for (int nt = 0; nt < 8; nt++) acc2[nt] = (floatx4){0.f, 0.f, 0.f, 0.f};
#pragma unroll 3
    for (int kt = 0; kt < 12; kt++) {
        bf16x8 a2 = *(const bf16x8*)&h1s[l15 * 392 + kt * 32 + quad * 8];
#pragma unroll
        for (int nt = 0; nt < 8; nt++) {
            bf16x8 bh = *(const bf16x8*)(f2Hi + (size_t)(nt * 16 + l15) * 384 + kt * 32 + quad * 8);
            acc2[nt] = __builtin_amdgcn_mfma_f32_16x16x32_bf16(a2, bh, acc2[nt], 0, 0, 0);
        }
    }

    // ---- h2 epilogue -> h2s (overlay; same-wave DS in-order) ----
#pragma unroll
    for (int nt = 0; nt < 8; nt++) {
        int col = nt * 16 + l15;
        float b = fc2b[col];
#pragma unroll
        for (int r = 0; r < 4; r++) {
            float v = acc2[nt][r] + b;
            v = v > 0.f ? v : 0.f;
            unsigned short hi = f2bf(v);
            unsigned short lo = f2bf(v - bf2f(hi));
            h2s[(quad * 4 + r) * 132 + col] = (unsigned)hi | ((unsigned)lo << 16);
        }
    }

    // ---- fc3: K=128, 4 col-tiles, 3-term ----
    floatx4 acc3[4];
#pragma unroll
    for (int nt = 0; nt < 4; nt++) acc3[nt] = (floatx4){0.f, 0.f, 0.f, 0.f};
#pragma unroll
    for (int kt = 0; kt < 4; kt++) {
        int base = l15 * 132 + kt * 32 + quad * 8;
        uint4 wa = *(const uint4*)&h2s[base];
        uint4 wb = *(const uint4*)&h2s[base + 4];
        bf16x8 a3h, a3l;
        unpack8(wa, wb, a3h, a3l);
#pragma unroll
        for (int nt = 0; nt < 4; nt++) {
            const size_t boff = (size_t)(nt * 16 + l15) * 128 + kt * 32 + quad * 8;
            bf16x8 bh = *(const bf16x8*)(f3Hi + boff);
            bf16x8 bl = *(const bf16x8*)(f3Lo + boff);
            acc3[nt] = __builtin_amdgcn_mfma_f32_16x16x32_bf16(a3h, bh, acc3[nt], 0, 0, 0);
            acc3[nt] = __builtin_amdgcn_mfma_f32_16x16x32_bf16(a3h, bl, acc3[nt], 0, 0, 0);
            acc3[nt] = __builtin_amdgcn_mfma_f32_16x16x32_bf16(a3l, bh, acc3[nt], 0, 0, 0);
        }
    }
#pragma unroll
    for (int nt = 0; nt < 4; nt++) {
        int col = nt * 16 + l15;
        float bv = fc3b[col];
#pragma unroll
        for (int r = 0; r < 4; r++) {
            int row = m0 + quad * 4 + r;
            if (row < M) out[(size_t)row * 64 + col] = acc3[nt][r] + bv;
        }
    }
}

// ============================================================
// Pre-split weights -> hi/lo bf16 planes, [n][k] layout
// ============================================================
__global__ void split_w(const float* __restrict__ W, int K, int Nc, int ldw,
                        unsigned short* __restrict__ hi, unsigned short* __restrict__ lo)
{
    int idx = blockIdx.x * 256 + threadIdx.x;
    if (idx >= K * Nc) return;
    int n = idx / K, k = idx - n * K;
    float v = W[(size_t)k * ldw + n];
    unsigned short h = f2bf(v);
    hi[idx] = h;
    lo[idx] = f2bf(v - bf2f(h));
}

// ============================================================
// rank-1 folds of x1/x2 paths into fc1
// ============================================================
__global__ void prep_u(const float* __restrict__ w1, const float* __restrict__ b1,
                       const float* __restrict__ w2, const float* __restrict__ b2,
                       const float* __restrict__ fc1w, const float* __restrict__ fc1b,
                       float* __restrict__ u1, float* __restrict__ u2, float* __restrict__ cb)
{
    int j = threadIdx.x + blockIdx.x * blockDim.x;
    if (j >= 384) return;
    float s1 = 0.f, s2 = 0.f, c = fc1b[j];
    for (int k = 0; k < 64; k++) {
        float wv = fc1w[k * 384 + j];
        s1 += w1[k] * wv; c += b1[k] * wv;
    }
    for (int k = 0; k < 64; k++) {
        float wv = fc1w[(64 + k) * 384 + j];
        s2 += w2[k] * wv; c += b2[k] * wv;
    }
    u1[j] = s1; u2[j] = s2; cb[j] = c;
}

// ============================================================
// CSR build
// ============================================================
__global__ __launch_bounds__(256)
void count_kernel(const int* __restrict__ ei, int E, int N, int* __restrict__ deg)
{
    int t = blockIdx.x * 256 + threadIdx.x;
    int total = E + N;
    if (t >= total) return;
    int d = (t < E) ? ei[E + t] : (t - E);
    atomicAdd(&deg[d], 1);
}

__global__ __launch_bounds__(256)
void scan_blk(const int* __restrict__ deg, int* __restrict__ rowptr,
              int* __restrict__ bsums, int N)
{
    __shared__ int sh[256];
    int b = blockIdx.x, t = threadIdx.x;
    int base = b * 2048 + t * 8;
    int v[8]; int s = 0;
#pragma unroll
    for (int j = 0; j < 8; j++) {
        v[j] = (base + j < N) ? deg[base + j] : 0;
        s += v[j];
    }
    sh[t] = s; __syncthreads();
#pragma unroll
    for (int off = 1; off < 256; off <<= 1) {
        int x = (t >= off) ? sh[t - off] : 0;
        __syncthreads();
        sh[t] += x;
        __syncthreads();
    }
    if (t == 255) bsums[b] = sh[255];
    int run = (t > 0) ? sh[t - 1] : 0;
#pragma unroll
    for (int j = 0; j < 8; j++) {
        if (base + j < N) rowptr[base + j] = run;
        run += v[j];
    }
}

__global__ void scan_top(int* __restrict__ bsums, int NB)
{
    __shared__ int sh[256];
    int t = threadIdx.x;
    sh[t] = (t < NB) ? bsums[t] : 0;
    __syncthreads();
#pragma unroll
    for (int off = 1; off < 256; off <<= 1) {
        int x = (t >= off) ? sh[t - off] : 0;
        __syncthreads();
        sh[t] += x;
        __syncthreads();
    }
    if (t < NB) bsums[t] = (t > 0) ? sh[t - 1] : 0;
}

__global__ __launch_bounds__(256)
void scan_add(int* __restrict__ rowptr, int* __restrict__ cursor,
              const int* __restrict__ bsums, int N)
{
    int i = blockIdx.x * 256 + threadIdx.x;
    if (i >= N) return;
    int v = rowptr[i] + bsums[i >> 11];
    rowptr[i] = v;
    cursor[i] = v;
}

__global__ __launch_bounds__(256)
void scatter_kernel(const int* __restrict__ ei, int E, int N,
                    const float* __restrict__ alS, const float* __restrict__ alD,
                    int* __restrict__ cursor, uint2* __restrict__ sev)
{
    int t = blockIdx.x * 256 + threadIdx.x;
    int total = E + N;
    if (t >= total) return;
    int s, d;
    if (t < E) { s = ei[t]; d = ei[E + t]; }
    else       { s = t - E; d = s; }
    float v = alS[s] + alD[d];
    v = v > 0.f ? v : NSLOPE * v;
    float ex = expf(v);
    int pos = atomicAdd(&cursor[d], 1);
    sev[pos] = make_uint2((unsigned)s, __builtin_bit_cast(unsigned, ex));
}

// ============================================================
// Gather-aggregate + normalize + bias -> x3
// ============================================================
__global__ __launch_bounds__(256)
void aggregate_kernel(const int* __restrict__ rowptr, const int* __restrict__ cursor,
                      const uint2* __restrict__ sev,
                      const float* __restrict__ h, const float* __restrict__ gatb,
                      float* __restrict__ x3, int N)
{
    int node = blockIdx.x * 4 + (threadIdx.x >> 6);
    int lane = threadIdx.x & 63;
    if (node >= N) return;
    int start = rowptr[node];
    int end   = cursor[node];
    float accv = 0.f, den = 0.f;
    for (int p = start; p < end; p += 64) {
        int idx = p + lane;
        uint2 se = make_uint2(0u, 0u);
        if (idx < end) se = sev[idx];
        int si = (int)se.x;
        float ex = __builtin_bit_cast(float, se.y);
        int cnt = end - p; if (cnt > 64) cnt = 64;
        int j = 0;
        for (; j + 4 <= cnt; j += 4) {
            int   s0 = __shfl(si, j),     s1 = __shfl(si, j + 1);
            int   s2 = __shfl(si, j + 2), s3 = __shfl(si, j + 3);
            float e0 = __shfl(ex, j),     e1 = __shfl(ex, j + 1);
            float e2 = __shfl(ex, j + 2), e3 = __shfl(ex, j + 3);
            float h0 = h[(size_t)s0 * 64 + lane];
            float h1 = h[(size_t)s1 * 64 + lane];
            float h2 = h[(size_t)s2 * 64 + lane];
            float h3 = h[(size_t)s3 * 64 + lane];
            den  += (e0 + e1) + (e2 + e3);
            accv += e0 * h0; accv += e1 * h1; accv += e2 * h2; accv += e3 * h3;
        }
        for (; j < cnt; j++) {
            int   sj = __shfl(si, j);
            float ej = __shfl(ex, j);
            den += ej;
            accv += ej * h[(size_t)sj * 64 + lane];
        }
    }
    x3[(size_t)node * 64 + lane] = accv / (den + 1e-16f) + gatb[lane];
}

extern "C" void kernel_launch(void* const* d_in, const int* in_sizes, int n_in,
                              void* d_out, int out_size, void* d_ws, size_t ws_size,
                              hipStream_t stream)
{
    const float* x      = (const float*)d_in[0];
    const int*   ei     = (const int*)d_in[1];
    const float* w1     = (const float*)d_in[2];
    const float* b1     = (const float*)d_in[3];
    const float* w2     = (const float*)d_in[4];
    const float* b2     = (const float*)d_in[5];
    const float* gat_w  = (const float*)d_in[6];
    const float* gat_as = (const float*)d_in[7];
    const float* gat_ad = (const float*)d_in[8];
    const float* gat_b  = (const float*)d_in[9];
    const float* fc1w   = (const float*)d_in[10];
    const float* fc1b   = (const float*)d_in[11];
    const float* fc2w   = (const float*)d_in[12];
    const float* fc2b   = (const float*)d_in[13];
    const float* fc3w   = (const float*)d_in[14];
    const float* fc3b   = (const float*)d_in[15];

    const int N = in_sizes[0] / 130;
    const int E = in_sizes[1] / 2;
    const int total = E + N;
    float* out = (float*)d_out;

    // ---- workspace layout ----
    float* ws = (float*)d_ws;
    size_t off = 0;
    float* h      = ws + off; off += (size_t)N * 64;
    float* x3     = ws + off; off += (size_t)N * 64;
    float* alS    = ws + off; off += (size_t)N;
    float* alD    = ws + off; off += (size_t)N;
    float* u1     = ws + off; off += 512;
    float* u2     = ws + off; off += 512;
    float* cb     = ws + off; off += 512;
    int*   deg    = (int*)(ws + off); off += (size_t)N;
    int*   rowptr = (int*)(ws + off); off += (size_t)N;
    int*   cursor = (int*)(ws + off); off += (size_t)N;
    int*   bsums  = (int*)(ws + off); off += 512;
    uint2* sev    = (uint2*)(ws + off); off += (size_t)total * 2;
    unsigned short* gatHi = (unsigned short*)(ws + off); off += 4096;   // 64*128
    unsigned short* gatLo = (unsigned short*)(ws + off); off += 4096;
    unsigned short* f1Hi  = (unsigned short*)(ws + off); off += 12288;  // 384*64
    unsigned short* f1Lo  = (unsigned short*)(ws + off); off += 12288;
    unsigned short* f2Hi  = (unsigned short*)(ws + off); off += 24576;  // 128*384
    unsigned short* f2Lo  = (unsigned short*)(ws + off); off += 24576;
    unsigned short* f3Hi  = (unsigned short*)(ws + off); off += 4096;   // 64*128
    unsigned short* f3Lo  = (unsigned short*)(ws + off); off += 4096;

    hipMemsetAsync(deg, 0, (size_t)N * sizeof(int), stream);

    prep_u<<<3, 128, 0, stream>>>(w1, b1, w2, b2, fc1w, fc1b, u1, u2, cb);
    split_w<<<(128 * 64 + 255) / 256, 256, 0, stream>>>(gat_w, 128, 64, 64, gatHi, gatLo);
    split_w<<<(64 * 384 + 255) / 256, 256, 0, stream>>>(fc1w + (size_t)128 * 384, 64, 384, 384, f1Hi, f1Lo);
    split_w<<<(384 * 128 + 255) / 256, 256, 0, stream>>>(fc2w, 384, 128, 128, f2Hi, f2Lo);
    split_w<<<(128 * 64 + 255) / 256, 256, 0, stream>>>(fc3w, 128, 64, 64, f3Hi, f3Lo);

    // h = x[:,2:] @ gat_w  + alpha_s/alpha_d fold
    hproj_kernel<<<(N + 127) / 128, 256, 0, stream>>>(x, gatHi, gatLo,
                                                      gat_as, gat_ad, h, alS, alD, N);

    // CSR build
    count_kernel<<<(total + 255) / 256, 256, 0, stream>>>(ei, E, N, deg);
    int NB = (N + 2047) / 2048;
    scan_blk<<<NB, 256, 0, stream>>>(deg, rowptr, bsums, N);
    scan_top<<<1, 256, 0, stream>>>(bsums, NB);
    scan_add<<<(N + 255) / 256, 256, 0, stream>>>(rowptr, cursor, bsums, N);
    scatter_kernel<<<(total + 255) / 256, 256, 0, stream>>>(ei, E, N, alS, alD,
                                                            cursor, sev);

    aggregate_kernel<<<(N + 3) / 4, 256, 0, stream>>>(rowptr, cursor, sev,
                                                      h, gat_b, x3, N);

    // fused MLP: fc1 -> fc2 -> fc3, wave-private
    fused_mlp<<<(N + 63) / 64, 256, 0, stream>>>(x3, x,
                                                 f1Hi, f2Hi, f3Hi, f3Lo,
                                                 cb, u1, u2, fc2b, fc3b, out, N);
}

// Round 7
// 451.794 us; speedup vs baseline: 1.1706x; 1.1706x over previous
//
#include <hip/hip_runtime.h>
#include <math.h>

#define NSLOPE 0.2f

typedef __attribute__((ext_vector_type(8)))  short bf16x8;
typedef __attribute__((ext_vector_type(4)))  float floatx4;
typedef __attribute__((ext_vector_type(16))) float floatx16;

__device__ __forceinline__ unsigned short f2bf(float f) {
    unsigned u = __builtin_bit_cast(unsigned, f);
    u += 0x7fff + ((u >> 16) & 1);          // RNE
    return (unsigned short)(u >> 16);
}
__device__ __forceinline__ float bf2f(unsigned short h) {
    unsigned u = (unsigned)h << 16;
    return __builtin_bit_cast(float, u);
}

__device__ __forceinline__ void split8(const float* v, bf16x8& hi, bf16x8& lo) {
#pragma unroll
    for (int j = 0; j < 8; j++) {
        unsigned short h = f2bf(v[j]);
        hi[j] = (short)h;
        lo[j] = (short)f2bf(v[j] - bf2f(h));
    }
}

// ============================================================
// h-projection + alpha fold; h stored as BF16 now.
// ============================================================
__global__ __launch_bounds__(256, 2)
void hproj_kernel(const float* __restrict__ x,
                  const unsigned short* __restrict__ Bhi,
                  const unsigned short* __restrict__ Blo,
                  const float* __restrict__ asrc, const float* __restrict__ adst,
                  unsigned short* __restrict__ hb, float* __restrict__ alS,
                  float* __restrict__ alD, int M)
{
    const int lane = threadIdx.x & 63;
    const int wv   = threadIdx.x >> 6;
    const int l15  = lane & 15;
    const int quad = lane >> 4;
    const int m0   = blockIdx.x * 128 + wv * 32;

    floatx4 acc[2][4];
#pragma unroll
    for (int mt = 0; mt < 2; mt++)
#pragma unroll
        for (int nt = 0; nt < 4; nt++) acc[mt][nt] = (floatx4){0.f, 0.f, 0.f, 0.f};

    int r0 = m0 + l15;      if (r0 >= M) r0 = M - 1;
    int r1 = m0 + 16 + l15; if (r1 >= M) r1 = M - 1;
    const float* a0 = x + (size_t)r0 * 130 + 2 + quad * 8;
    const float* a1 = x + (size_t)r1 * 130 + 2 + quad * 8;

#pragma unroll
    for (int kt = 0; kt < 4; kt++) {
        const int kb = kt * 32;
        float av[2][8];
#pragma unroll
        for (int j = 0; j < 4; j++) {
            float2 q0 = *(const float2*)(a0 + kb + 2 * j);
            float2 q1 = *(const float2*)(a1 + kb + 2 * j);
            av[0][2 * j] = q0.x; av[0][2 * j + 1] = q0.y;
            av[1][2 * j] = q1.x; av[1][2 * j + 1] = q1.y;
        }
        bf16x8 ah[2], al[2];
        split8(av[0], ah[0], al[0]);
        split8(av[1], ah[1], al[1]);
#pragma unroll
        for (int nt = 0; nt < 4; nt++) {
            const size_t boff = (size_t)(nt * 16 + l15) * 128 + kb + quad * 8;
            bf16x8 bh = *(const bf16x8*)(Bhi + boff);
            bf16x8 bl = *(const bf16x8*)(Blo + boff);
#pragma unroll
            for (int mt = 0; mt < 2; mt++) {
                acc[mt][nt] = __builtin_amdgcn_mfma_f32_16x16x32_bf16(ah[mt], bh, acc[mt][nt], 0, 0, 0);
                acc[mt][nt] = __builtin_amdgcn_mfma_f32_16x16x32_bf16(ah[mt], bl, acc[mt][nt], 0, 0, 0);
                acc[mt][nt] = __builtin_amdgcn_mfma_f32_16x16x32_bf16(al[mt], bh, acc[mt][nt], 0, 0, 0);
            }
        }
    }

    float as4[4], ad4[4];
#pragma unroll
    for (int nt = 0; nt < 4; nt++) {
        as4[nt] = asrc[nt * 16 + l15];
        ad4[nt] = adst[nt * 16 + l15];
    }

    float ps[2][4], pd[2][4];
#pragma unroll
    for (int mt = 0; mt < 2; mt++) {
#pragma unroll
        for (int r = 0; r < 4; r++) {
            int row = m0 + mt * 16 + quad * 4 + r;
            float s = 0.f, d = 0.f;
#pragma unroll
            for (int nt = 0; nt < 4; nt++) {
                float v = acc[mt][nt][r];
                s += v * as4[nt];
                d += v * ad4[nt];
                if (row < M) hb[(size_t)row * 64 + nt * 16 + l15] = f2bf(v);
            }
            ps[mt][r] = s; pd[mt][r] = d;
        }
    }
#pragma unroll
    for (int mt = 0; mt < 2; mt++)
#pragma unroll
        for (int r = 0; r < 4; r++) {
#pragma unroll
            for (int msk = 1; msk < 16; msk <<= 1) {
                ps[mt][r] += __shfl_xor(ps[mt][r], msk);
                pd[mt][r] += __shfl_xor(pd[mt][r], msk);
            }
        }
    if (l15 == 0) {
#pragma unroll
        for (int mt = 0; mt < 2; mt++)
#pragma unroll
            for (int r = 0; r < 4; r++) {
                int row = m0 + mt * 16 + quad * 4 + r;
                if (row < M) { alS[row] = ps[mt][r]; alD[row] = pd[mt][r]; }
            }
    }
}

// ============================================================
// Fused MLP v4: 32 rows/WAVE with 32x32x16 MFMA (2x FLOP per
// B-fragment load vs 16x16x32). 2-wave blocks (both waves hit
// identical weight addresses -> L1 reuse). Wave-private LDS,
// zero barriers.  h1: [32][392] bf16-hi; h2 overlay [32][136]
// bf16-hi (fc3 2-term: h2hi x (W3hi + W3lo)).
// A-frag: m=lane&31, k=(lane>>5)*8+j.  B-frag: n=lane&31, same k.
// D: col=lane&31, row=(reg&3)+8*(reg>>2)+4*(lane>>5).
// ============================================================
__global__ __launch_bounds__(128, 4)
void fused_mlp(const float* __restrict__ x3,
               const float* __restrict__ x,
               const unsigned short* __restrict__ f1Hi,
               const unsigned short* __restrict__ f2Hi,
               const unsigned short* __restrict__ f3Hi,
               const unsigned short* __restrict__ f3Lo,
               const float* __restrict__ cb, const float* __restrict__ u1,
               const float* __restrict__ u2, const float* __restrict__ fc2b,
               const float* __restrict__ fc3b,
               float* __restrict__ out, int M)
{
    __shared__ unsigned short smem[2 * 12544];            // 50176 B
    const int lane = threadIdx.x & 63;
    const int wv   = threadIdx.x >> 6;
    const int l31  = lane & 31;
    const int half = lane >> 5;
    const int m0   = blockIdx.x * 64 + wv * 32;

    unsigned short* h1s = smem + wv * 12544;              // [32][392]
    unsigned short* h2s = h1s;                            // [32][136] overlay

    // ---- fc1 A-frags from x3 (K=64): k = kt*16 + half*8 + j ----
    bf16x8 ah[4], al[4];
    {
        int r0 = m0 + l31; if (r0 >= M) r0 = M - 1;
        const float* a0 = x3 + (size_t)r0 * 64 + half * 8;
#pragma unroll
        for (int kt = 0; kt < 4; kt++) {
            float av[8];
            float4 qa = *(const float4*)(a0 + kt * 16);
            float4 qb = *(const float4*)(a0 + kt * 16 + 4);
            av[0]=qa.x; av[1]=qa.y; av[2]=qa.z; av[3]=qa.w;
            av[4]=qb.x; av[5]=qb.y; av[6]=qb.z; av[7]=qb.w;
            split8(av, ah[kt], al[kt]);
        }
    }

    // rank-1 row scalars for the 16 rows this lane's D-regs cover
    float xv0[16], xv1[16];
#pragma unroll
    for (int reg = 0; reg < 16; reg++) {
        int rl  = (reg & 3) + 8 * (reg >> 2) + 4 * half;
        int row = m0 + rl;
        float2 xv = {0.f, 0.f};
        if (row < M) xv = *(const float2*)(x + (size_t)row * 130);
        xv0[reg] = xv.x; xv1[reg] = xv.y;
    }

    // ---- fc1: 12 n-tiles of 32 cols, 2-term (A hi+lo x B hi) ----
#pragma unroll 2
    for (int nt = 0; nt < 12; nt++) {
        floatx16 acc = (floatx16)(0.f);
        const int col = nt * 32 + l31;
        const unsigned short* bp = f1Hi + (size_t)col * 64 + half * 8;
#pragma unroll
        for (int kt = 0; kt < 4; kt++) {
            bf16x8 bh = *(const bf16x8*)(bp + kt * 16);
            acc = __builtin_amdgcn_mfma_f32_32x32x16_bf16(ah[kt], bh, acc, 0, 0, 0);
            acc = __builtin_amdgcn_mfma_f32_32x32x16_bf16(al[kt], bh, acc, 0, 0, 0);
        }
        float c0 = cb[col], q1 = u1[col], q2 = u2[col];
#pragma unroll
        for (int reg = 0; reg < 16; reg++) {
            int rl = (reg & 3) + 8 * (reg >> 2) + 4 * half;
            float v = acc[reg] + c0 + xv0[reg] * q1 + xv1[reg] * q2;
            v = v > 0.f ? v : 0.f;
            h1s[rl * 392 + col] = f2bf(v);
        }
    }

    // ---- fc2: K=384, 4 n-tiles, 1-term (h1hi x W2hi) ----
    floatx16 acc2[4];
#pragma unroll
    for (int nt = 0; nt < 4; nt++) acc2[nt] = (floatx16)(0.f);
#pragma unroll 4
    for (int kt = 0; kt < 24; kt++) {
        bf16x8 a2 = *(const bf16x8*)&h1s[l31 * 392 + kt * 16 + half * 8];
#pragma unroll
        for (int nt = 0; nt < 4; nt++) {
            bf16x8 bh = *(const bf16x8*)(f2Hi + (size_t)(nt * 32 + l31) * 384 + kt * 16 + half * 8);
            acc2[nt] = __builtin_amdgcn_mfma_f32_32x32x16_bf16(a2, bh, acc2[nt], 0, 0, 0);
        }
    }

    // ---- fc2 epilogue -> h2s bf16-hi (overlay; same-wave DS in-order) ----
#pragma unroll
    for (int nt = 0; nt < 4; nt++) {
        int col = nt * 32 + l31;
        float b = fc2b[col];
#pragma unroll
        for (int reg = 0; reg < 16; reg++) {
            int rl = (reg & 3) + 8 * (reg >> 2) + 4 * half;
            float v = acc2[nt][reg] + b;
            v = v > 0.f ? v : 0.f;
            h2s[rl * 136 + col] = f2bf(v);
        }
    }

    // ---- fc3: K=128, 2 n-tiles, 2-term (h2hi x (W3hi + W3lo)) ----
    floatx16 acc3[2];
    acc3[0] = (floatx16)(0.f);
    acc3[1] = (floatx16)(0.f);
#pragma unroll 2
    for (int kt = 0; kt < 8; kt++) {
        bf16x8 a3 = *(const bf16x8*)&h2s[l31 * 136 + kt * 16 + half * 8];
#pragma unroll
        for (int nt = 0; nt < 2; nt++) {
            const size_t boff = (size_t)(nt * 32 + l31) * 128 + kt * 16 + half * 8;
            bf16x8 bh = *(const bf16x8*)(f3Hi + boff);
            bf16x8 bl = *(const bf16x8*)(f3Lo + boff);
            acc3[nt] = __builtin_amdgcn_mfma_f32_32x32x16_bf16(a3, bh, acc3[nt], 0, 0, 0);
            acc3[nt] = __builtin_amdgcn_mfma_f32_32x32x16_bf16(a3, bl, acc3[nt], 0, 0, 0);
        }
    }
#pragma unroll
    for (int nt = 0; nt < 2; nt++) {
        int col = nt * 32 + l31;
        float bv = fc3b[col];
#pragma unroll
        for (int reg = 0; reg < 16; reg++) {
            int rl  = (reg & 3) + 8 * (reg >> 2) + 4 * half;
            int row = m0 + rl;
            if (row < M) out[(size_t)row * 64 + col] = acc3[nt][reg] + bv;
        }
    }
}

// ============================================================
// Pre-split weights -> hi/lo bf16 planes, [n][k] layout
// ============================================================
__global__ void split_w(const float* __restrict__ W, int K, int Nc, int ldw,
                        unsigned short* __restrict__ hi, unsigned short* __restrict__ lo)
{
    int idx = blockIdx.x * 256 + threadIdx.x;
    if (idx >= K * Nc) return;
    int n = idx / K, k = idx - n * K;
    float v = W[(size_t)k * ldw + n];
    unsigned short h = f2bf(v);
    hi[idx] = h;
    lo[idx] = f2bf(v - bf2f(h));
}

// ============================================================
// rank-1 folds of x1/x2 paths into fc1
// ============================================================
__global__ void prep_u(const float* __restrict__ w1, const float* __restrict__ b1,
                       const float* __restrict__ w2, const float* __restrict__ b2,
                       const float* __restrict__ fc1w, const float* __restrict__ fc1b,
                       float* __restrict__ u1, float* __restrict__ u2, float* __restrict__ cb)
{
    int j = threadIdx.x + blockIdx.x * blockDim.x;
    if (j >= 384) return;
    float s1 = 0.f, s2 = 0.f, c = fc1b[j];
    for (int k = 0; k < 64; k++) {
        float wv = fc1w[k * 384 + j];
        s1 += w1[k] * wv; c += b1[k] * wv;
    }
    for (int k = 0; k < 64; k++) {
        float wv = fc1w[(64 + k) * 384 + j];
        s2 += w2[k] * wv; c += b2[k] * wv;
    }
    u1[j] = s1; u2[j] = s2; cb[j] = c;
}

// ============================================================
// CSR build
// ============================================================
__global__ __launch_bounds__(256)
void count_kernel(const int* __restrict__ ei, int E, int N, int* __restrict__ deg)
{
    int t = blockIdx.x * 256 + threadIdx.x;
    int total = E + N;
    if (t >= total) return;
    int d = (t < E) ? ei[E + t] : (t - E);
    atomicAdd(&deg[d], 1);
}

__global__ __launch_bounds__(256)
void scan_blk(const int* __restrict__ deg, int* __restrict__ rowptr,
              int* __restrict__ bsums, int N)
{
    __shared__ int sh[256];
    int b = blockIdx.x, t = threadIdx.x;
    int base = b * 2048 + t * 8;
    int v[8]; int s = 0;
#pragma unroll
    for (int j = 0; j < 8; j++) {
        v[j] = (base + j < N) ? deg[base + j] : 0;
        s += v[j];
    }
    sh[t] = s; __syncthreads();
#pragma unroll
    for (int off = 1; off < 256; off <<= 1) {
        int x = (t >= off) ? sh[t - off] : 0;
        __syncthreads();
        sh[t] += x;
        __syncthreads();
    }
    if (t == 255) bsums[b] = sh[255];
    int run = (t > 0) ? sh[t - 1] : 0;
#pragma unroll
    for (int j = 0; j < 8; j++) {
        if (base + j < N) rowptr[base + j] = run;
        run += v[j];
    }
}

__global__ void scan_top(int* __restrict__ bsums, int NB)
{
    __shared__ int sh[256];
    int t = threadIdx.x;
    sh[t] = (t < NB) ? bsums[t] : 0;
    __syncthreads();
#pragma unroll
    for (int off = 1; off < 256; off <<= 1) {
        int x = (t >= off) ? sh[t - off] : 0;
        __syncthreads();
        sh[t] += x;
        __syncthreads();
    }
    if (t < NB) bsums[t] = (t > 0) ? sh[t - 1] : 0;
}

__global__ __launch_bounds__(256)
void scan_add(int* __restrict__ rowptr, int* __restrict__ cursor,
              const int* __restrict__ bsums, int N)
{
    int i = blockIdx.x * 256 + threadIdx.x;
    if (i >= N) return;
    int v = rowptr[i] + bsums[i >> 11];
    rowptr[i] = v;
    cursor[i] = v;
}

__global__ __launch_bounds__(256)
void scatter_kernel(const int* __restrict__ ei, int E, int N,
                    const float* __restrict__ alS, const float* __restrict__ alD,
                    int* __restrict__ cursor, uint2* __restrict__ sev)
{
    int t = blockIdx.x * 256 + threadIdx.x;
    int total = E + N;
    if (t >= total) return;
    int s, d;
    if (t < E) { s = ei[t]; d = ei[E + t]; }
    else       { s = t - E; d = s; }
    float v = alS[s] + alD[d];
    v = v > 0.f ? v : NSLOPE * v;
    float ex = expf(v);
    int pos = atomicAdd(&cursor[d], 1);
    sev[pos] = make_uint2((unsigned)s, __builtin_bit_cast(unsigned, ex));
}

// ============================================================
// Gather-aggregate v2: HALF-WAVE (32 lanes) per node; h is bf16,
// each lane loads one u32 = 2 columns. 4x unrolled gathers.
// ============================================================
__global__ __launch_bounds__(256)
void aggregate_kernel(const int* __restrict__ rowptr, const int* __restrict__ cursor,
                      const uint2* __restrict__ sev,
                      const unsigned int* __restrict__ hb32,   // h as [N][32] u32 (2 bf16 each)
                      const float* __restrict__ gatb,
                      float* __restrict__ x3, int N)
{
    int node = blockIdx.x * 8 + (threadIdx.x >> 5);
    int l    = threadIdx.x & 31;
    int hsel = threadIdx.x & 32;              // 0 or 32: shfl source base
    if (node >= N) return;
    int start = rowptr[node];
    int end   = cursor[node];
    float ax = 0.f, ay = 0.f, den = 0.f;
    for (int p = start; p < end; p += 32) {
        int idx = p + l;
        uint2 se = (idx < end) ? sev[idx] : make_uint2(0u, 0u);
        int si = (int)se.x;
        float ex = __builtin_bit_cast(float, se.y);
        int cnt = end - p; if (cnt > 32) cnt = 32;
        int j = 0;
        for (; j + 4 <= cnt; j += 4) {
            int   s0 = __shfl(si, hsel | j),       s1 = __shfl(si, hsel | (j + 1));
            int   s2 = __shfl(si, hsel | (j + 2)), s3 = __shfl(si, hsel | (j + 3));
            float e0 = __shfl(ex, hsel | j),       e1 = __shfl(ex, hsel | (j + 1));
            float e2 = __shfl(ex, hsel | (j + 2)), e3 = __shfl(ex, hsel | (j + 3));
            unsigned w0 = hb32[(size_t)s0 * 32 + l];
            unsigned w1 = hb32[(size_t)s1 * 32 + l];
            unsigned w2 = hb32[(size_t)s2 * 32 + l];
            unsigned w3 = hb32[(size_t)s3 * 32 + l];
            den += (e0 + e1) + (e2 + e3);
            ax += e0 * bf2f((unsigned short)(w0 & 0xFFFFu));
            ay += e0 * bf2f((unsigned short)(w0 >> 16));
            ax += e1 * bf2f((unsigned short)(w1 & 0xFFFFu));
            ay += e1 * bf2f((unsigned short)(w1 >> 16));
            ax += e2 * bf2f((unsigned short)(w2 & 0xFFFFu));
            ay += e2 * bf2f((unsigned short)(w2 >> 16));
            ax += e3 * bf2f((unsigned short)(w3 & 0xFFFFu));
            ay += e3 * bf2f((unsigned short)(w3 >> 16));
        }
        for (; j < cnt; j++) {
            int   sj = __shfl(si, hsel | j);
            float ej = __shfl(ex, hsel | j);
            unsigned w = hb32[(size_t)sj * 32 + l];
            den += ej;
            ax += ej * bf2f((unsigned short)(w & 0xFFFFu));
            ay += ej * bf2f((unsigned short)(w >> 16));
        }
    }
    float inv = 1.f / (den + 1e-16f);
    float2 o;
    o.x = ax * inv + gatb[2 * l];
    o.y = ay * inv + gatb[2 * l + 1];
    *(float2*)&x3[(size_t)node * 64 + 2 * l] = o;
}

extern "C" void kernel_launch(void* const* d_in, const int* in_sizes, int n_in,
                              void* d_out, int out_size, void* d_ws, size_t ws_size,
                              hipStream_t stream)
{
    const float* x      = (const float*)d_in[0];
    const int*   ei     = (const int*)d_in[1];
    const float* w1     = (const float*)d_in[2];
    const float* b1     = (const float*)d_in[3];
    const float* w2     = (const float*)d_in[4];
    const float* b2     = (const float*)d_in[5];
    const float* gat_w  = (const float*)d_in[6];
    const float* gat_as = (const float*)d_in[7];
    const float* gat_ad = (const float*)d_in[8];
    const float* gat_b  = (const float*)d_in[9];
    const float* fc1w   = (const float*)d_in[10];
    const float* fc1b   = (const float*)d_in[11];
    const float* fc2w   = (const float*)d_in[12];
    const float* fc2b   = (const float*)d_in[13];
    const float* fc3w   = (const float*)d_in[14];
    const float* fc3b   = (const float*)d_in[15];

    const int N = in_sizes[0] / 130;
    const int E = in_sizes[1] / 2;
    const int total = E + N;
    float* out = (float*)d_out;

    // ---- workspace layout ----
    float* ws = (float*)d_ws;
    size_t off = 0;
    unsigned short* hb = (unsigned short*)(ws + off); off += (size_t)N * 32;  // h bf16 [N][64]
    float* x3     = ws + off; off += (size_t)N * 64;
    float* alS    = ws + off; off += (size_t)N;
    float* alD    = ws + off; off += (size_t)N;
    float* u1     = ws + off; off += 512;
    float* u2     = ws + off; off += 512;
    float* cb     = ws + off; off += 512;
    int*   deg    = (int*)(ws + off); off += (size_t)N;
    int*   rowptr = (int*)(ws + off); off += (size_t)N;
    int*   cursor = (int*)(ws + off); off += (size_t)N;
    int*   bsums  = (int*)(ws + off); off += 512;
    uint2* sev    = (uint2*)(ws + off); off += (size_t)total * 2;
    unsigned short* gatHi = (unsigned short*)(ws + off); off += 4096;   // 64*128
    unsigned short* gatLo = (unsigned short*)(ws + off); off += 4096;
    unsigned short* f1Hi  = (unsigned short*)(ws + off); off += 12288;  // 384*64
    unsigned short* f1Lo  = (unsigned short*)(ws + off); off += 12288;
    unsigned short* f2Hi  = (unsigned short*)(ws + off); off += 24576;  // 128*384
    unsigned short* f2Lo  = (unsigned short*)(ws + off); off += 24576;
    unsigned short* f3Hi  = (unsigned short*)(ws + off); off += 4096;   // 64*128
    unsigned short* f3Lo  = (unsigned short*)(ws + off); off += 4096;

    hipMemsetAsync(deg, 0, (size_t)N * sizeof(int), stream);

    prep_u<<<3, 128, 0, stream>>>(w1, b1, w2, b2, fc1w, fc1b, u1, u2, cb);
    split_w<<<(128 * 64 + 255) / 256, 256, 0, stream>>>(gat_w, 128, 64, 64, gatHi, gatLo);
    split_w<<<(64 * 384 + 255) / 256, 256, 0, stream>>>(fc1w + (size_t)128 * 384, 64, 384, 384, f1Hi, f1Lo);
    split_w<<<(384 * 128 + 255) / 256, 256, 0, stream>>>(fc2w, 384, 128, 128, f2Hi, f2Lo);
    split_w<<<(128 * 64 + 255) / 256, 256, 0, stream>>>(fc3w, 128, 64, 64, f3Hi, f3Lo);

    // h = x[:,2:] @ gat_w (bf16 out) + alpha_s/alpha_d fold
    hproj_kernel<<<(N + 127) / 128, 256, 0, stream>>>(x, gatHi, gatLo,
                                                      gat_as, gat_ad, hb, alS, alD, N);

    // CSR build
    count_kernel<<<(total + 255) / 256, 256, 0, stream>>>(ei, E, N, deg);
    int NB = (N + 2047) / 2048;
    scan_blk<<<NB, 256, 0, stream>>>(deg, rowptr, bsums, N);
    scan_top<<<1, 256, 0, stream>>>(bsums, NB);
    scan_add<<<(N + 255) / 256, 256, 0, stream>>>(rowptr, cursor, bsums, N);
    scatter_kernel<<<(total + 255) / 256, 256, 0, stream>>>(ei, E, N, alS, alD,
                                                            cursor, sev);

    aggregate_kernel<<<(N + 7) / 8, 256, 0, stream>>>(rowptr, cursor, sev,
                                                      (const unsigned int*)hb,
                                                      gat_b, x3, N);

    // fused MLP: fc1 -> fc2 -> fc3, 32 rows/wave, 32x32x16 MFMA
    fused_mlp<<<(N + 63) / 64, 128, 0, stream>>>(x3, x,
                                                 f1Hi, f2Hi, f3Hi, f3Lo,
                                                 cb, u1, u2, fc2b, fc3b, out, N);
}